// Round 9
// baseline (720.427 us; speedup 1.0000x reference)
//
#include <hip/hip_runtime.h>
#include <hip/hip_bf16.h>
#include <hip/hip_fp16.h>

// Problem constants (from setup_inputs): B=4, T=4096, D=1024, H=1024
#define B_ 4
#define T_ 4096
#define D_ 1024
#define H_ 1024
#define M_ (B_ * T_)   // 16384

typedef __attribute__((ext_vector_type(8))) short short8;   // 8 bf16 = 4 VGPRs (MFMA A/B frag)
typedef __attribute__((ext_vector_type(4))) float f32x4;    // MFMA C/D frag

// ---------------- fp32 -> bf16 (RNE) ----------------
__device__ __forceinline__ unsigned short f2bf(float f) {
    unsigned int u = __float_as_uint(f);
    u += 0x7fffu + ((u >> 16) & 1u);
    return (unsigned short)(u >> 16);
}

// Convert + PERMUTE into k-major fragment-subtile-lane order (unchanged R8).
__global__ __launch_bounds__(256) void convert_all(
    const float* __restrict__ x, const float* __restrict__ wz, const float* __restrict__ wh,
    unsigned short* __restrict__ xbp, unsigned short* __restrict__ wcbp)
{
    int i = blockIdx.x * 256 + threadIdx.x;
    const float* srcrow;
    unsigned short* dst;
    if (i < 2097152) {               // x: 16384x1024 -> 2,097,152 lane-slots
        int l = i & 63, s = i >> 6;
        int c = s & 31, r = s >> 5;  // r = rowblk 0..1023
        int row = r * 16 + (l & 15);
        int k   = c * 32 + (l >> 4) * 8;
        srcrow = x + (size_t)row * D_ + k;
        dst = xbp + ((size_t)(c * 1024 + r) * 64 + l) * 8;   // k-major
    } else {                         // wcb: 2048x1024 -> 262,144 lane-slots
        int j = i - 2097152;
        int l = j & 63, s = j >> 6;
        int c = s & 31, r = s >> 5;  // r = int-rowblk 0..127
        int ir = r * 16 + (l & 15);  // interleaved int-row 0..2047
        int a = ir >> 5, wi = ir & 31;
        const float* m = (wi < 16) ? wz : wh;
        int srow = a * 16 + (wi & 15);
        int k = c * 32 + (l >> 4) * 8;
        srcrow = m + (size_t)srow * D_ + k;
        dst = wcbp + ((size_t)(c * 128 + r) * 64 + l) * 8;   // k-major
    }
    float4 f0 = ((const float4*)srcrow)[0];
    float4 f1 = ((const float4*)srcrow)[1];
    ushort4 u0, u1;
    u0.x = f2bf(f0.x); u0.y = f2bf(f0.y); u0.z = f2bf(f0.z); u0.w = f2bf(f0.w);
    u1.x = f2bf(f1.x); u1.y = f2bf(f1.y); u1.z = f2bf(f1.z); u1.w = f2bf(f1.w);
    ((ushort4*)dst)[0] = u0;
    ((ushort4*)dst)[1] = u1;
}

// ---------------- fused GEMM + epilogue + decoupled-lookback scan + replay ----
// GEMM mechanics = R8 flatmm (no LDS/barriers, ping-pong reg prefetch).
// bid = nbg*128 + mbw (NO swizzle):
//   * XCD = bid%8 = mbw%8 -> all 8 nbg blocks of an mbw land on ONE XCD (A L2-reuse).
//   * per-nbg scan chain = CONTIGUOUS bid range [128*nbg, 128*nbg+128): any in-order
//     dispatch prefix contains only self-sufficient chains -> spin-wait deadlock-free
//     at ANY residency (rocPRIM-lookback precedent for in-order dispatch).
// Handoff: hpub[mbw][1024 cols] + flags[bid] via __hip_atomic_* AGENT scope
// (device-coherent; avoids R7's stale plain-load failure). Batch starts (mbw%32==0)
// seed from g(h0) and wait on nothing. av (a,v half2) stays in REGISTERS: the 64MB
// av16 write + 64MB read and the pass3 kernel are eliminated.
__global__ __launch_bounds__(256, 2) void gemm_scan_kernel(
    const unsigned short* __restrict__ xbp,  // k-major perm [32 c][1024 rb][64][8]
    const unsigned short* __restrict__ wcbp, // k-major perm [32 c][128 irb][64][8]
    const float* __restrict__ bz,
    const float* __restrict__ bh,
    const float* __restrict__ h0,            // [B][H]
    float* __restrict__ hpub,                // [128 mbw][1024 cols]
    int* __restrict__ flags,                 // [1024 bids], zeroed per launch
    float* __restrict__ out)                 // [B,T,H] fp32
{
    const int tid  = threadIdx.x;
    const int lane = tid & 63;
    const int w    = __builtin_amdgcn_readfirstlane(tid >> 6); // wave id 0..3
    const int r16  = lane & 15;
    const int q    = lane >> 4;

    const int bid = blockIdx.x;              // 0..1023
    const int nbg = bid >> 7;                // 0..7
    const int mbw = bid & 127;               // 0..127
    const int nbw = nbg * 4 + w;             // 0..31
    const int b   = mbw >> 5;                // batch id

    // per-lane fragment bases (contiguous 1KB per fragment)
    const unsigned short* gA = xbp  + (size_t)(mbw * 8) * 512 + lane * 8;
    const unsigned short* gB = wcbp + (size_t)(nbw * 4) * 512 + lane * 8;

#define LOADK(FA, FB, c) do { \
    const unsigned short* _a = gA + (size_t)(c) * 524288; \
    const unsigned short* _b = gB + (size_t)(c) * 65536; \
    _Pragma("unroll") \
    for (int m = 0; m < 8; ++m) FA[m] = *(const short8*)(_a + m * 512); \
    _Pragma("unroll") \
    for (int n = 0; n < 4; ++n) FB[n] = *(const short8*)(_b + n * 512); \
} while (0)

#define MFMA32(FA, FB) do { \
    __builtin_amdgcn_s_setprio(1); \
    _Pragma("unroll") \
    for (int m = 0; m < 8; ++m) \
        _Pragma("unroll") \
        for (int n = 0; n < 4; ++n) \
            acc[m][n] = __builtin_amdgcn_mfma_f32_16x16x32_bf16(FA[m], FB[n], acc[m][n], 0, 0, 0); \
    __builtin_amdgcn_s_setprio(0); \
} while (0)

    f32x4 acc[8][4] = {};
    short8 fa0[8], fb0[4], fa1[8], fb1[4];

    LOADK(fa0, fb0, 0);
    for (int cc = 0; cc < 32; cc += 2) {
        LOADK(fa1, fb1, cc + 1);             // prefetch next kblk while MFMA runs
        MFMA32(fa0, fb0);
        if (cc < 30) LOADK(fa0, fb0, cc + 2);
        MFMA32(fa1, fb1);
    }

    // ---------------- epilogue: av -> REGISTERS + chunk composites ------------
    // C/D layout: col = lane&15, row = q*4 + rr  [verified m89/m91].
    // acc[mf][0/1] = z/h for col ncol0; acc[mf][2/3] = z/h for ncol0+16.
    const int mrow0 = mbw * 128;
    const int ncol0 = nbw * 32 + r16;
    const float bzv0 = bz[ncol0],      bhv0 = bh[ncol0];
    const float bzv1 = bz[ncol0 + 16], bhv1 = bh[ncol0 + 16];

    __half2 av[64];                          // [(gg*2+hh)*16 + mm*4 + rr]
    float CAh[2][2], CVh[2][2];              // [hh][gg] chunk composites
#pragma unroll
    for (int hh = 0; hh < 2; ++hh) {         // two 64-row chunks per wave
        float CA0 = 1.0f, CV0 = 0.0f, CA1 = 1.0f, CV1 = 0.0f;
#pragma unroll
        for (int mm = 0; mm < 4; ++mm) {
            const int mf = hh * 4 + mm;
            float LA0 = 1.0f, LV0 = 0.0f, LA1 = 1.0f, LV1 = 0.0f;
#pragma unroll
            for (int rr = 0; rr < 4; ++rr) {
                {   // ---- gg = 0 ----
                    float kv = acc[mf][0][rr] + bzv0;
                    float hv = acc[mf][1][rr] + bhv0;
                    float tk = __expf(-fabsf(kv));
                    float ik = 1.0f / (1.0f + tk);
                    float sig = (kv >= 0.0f) ? ik : tk * ik;         // sigmoid(k)
                    float ac  = (kv >= 0.0f) ? tk * ik : ik;         // sigmoid(-k)
                    float th = __expf(-fabsf(hv));
                    float ih = 1.0f / (1.0f + th);
                    float gh = (hv >= 0.0f) ? (hv + 0.5f) : th * ih; // g(hb)
                    float vv = sig * gh;
                    av[(0 * 2 + hh) * 16 + mm * 4 + rr] = __floats2half2_rn(ac, vv);
                    LV0 = ac * LV0 + vv;     // ascending t composition
                    LA0 = ac * LA0;
                }
                {   // ---- gg = 1 ----
                    float kv = acc[mf][2][rr] + bzv1;
                    float hv = acc[mf][3][rr] + bhv1;
                    float tk = __expf(-fabsf(kv));
                    float ik = 1.0f / (1.0f + tk);
                    float sig = (kv >= 0.0f) ? ik : tk * ik;
                    float ac  = (kv >= 0.0f) ? tk * ik : ik;
                    float th = __expf(-fabsf(hv));
                    float ih = 1.0f / (1.0f + th);
                    float gh = (hv >= 0.0f) ? (hv + 0.5f) : th * ih;
                    float vv = sig * gh;
                    av[(1 * 2 + hh) * 16 + mm * 4 + rr] = __floats2half2_rn(ac, vv);
                    LV1 = ac * LV1 + vv;
                    LA1 = ac * LA1;
                }
            }
            // order-preserving combine across q (lower lane index = earlier rows)
#pragma unroll
            for (int mask = 16; mask <= 32; mask <<= 1) {
                float PA0 = __shfl_xor(LA0, mask);
                float PV0 = __shfl_xor(LV0, mask);
                float PA1 = __shfl_xor(LA1, mask);
                float PV1 = __shfl_xor(LV1, mask);
                if (lane & mask) {
                    LV0 = LA0 * PV0 + LV0; LA0 = LA0 * PA0;
                    LV1 = LA1 * PV1 + LV1; LA1 = LA1 * PA1;
                } else {
                    LV0 = PA0 * LV0 + PV0; LA0 = PA0 * LA0;
                    LV1 = PA1 * LV1 + PV1; LA1 = PA1 * LA1;
                }
            }
            CV0 = LA0 * CV0 + LV0; CA0 = LA0 * CA0;
            CV1 = LA1 * CV1 + LV1; CA1 = LA1 * CA1;
        }
        CAh[hh][0] = CA0; CVh[hh][0] = CV0;  // all lanes hold full 64-row composite
        CAh[hh][1] = CA1; CVh[hh][1] = CV1;
    }

    // ---------------- lookback: acquire h_in, publish h_out ----------------
    float hin0, hin1;
    if ((mbw & 31) == 0) {                   // batch start: seed from g(h0)
        float x0 = h0[b * H_ + ncol0];
        float x1 = h0[b * H_ + ncol0 + 16];
        if (x0 >= 0.0f) hin0 = x0 + 0.5f;
        else { float t = __expf(x0); hin0 = t / (1.0f + t); }
        if (x1 >= 0.0f) hin1 = x1 + 0.5f;
        else { float t = __expf(x1); hin1 = t / (1.0f + t); }
    } else {
        if (tid == 0) {
            while (__hip_atomic_load(&flags[bid - 1], __ATOMIC_ACQUIRE,
                                     __HIP_MEMORY_SCOPE_AGENT) == 0)
                __builtin_amdgcn_s_sleep(8);
        }
        __syncthreads();                     // all threads see flag acquired
        hin0 = __hip_atomic_load(&hpub[(mbw - 1) * 1024 + ncol0],
                                 __ATOMIC_RELAXED, __HIP_MEMORY_SCOPE_AGENT);
        hin1 = __hip_atomic_load(&hpub[(mbw - 1) * 1024 + ncol0 + 16],
                                 __ATOMIC_RELAXED, __HIP_MEMORY_SCOPE_AGENT);
    }
    // chunk entry states and block-exit state (composites only — no replay needed)
    const float e10 = CAh[0][0] * hin0 + CVh[0][0];   // entry of chunk hh=1
    const float e11 = CAh[0][1] * hin1 + CVh[0][1];
    const float ho0 = CAh[1][0] * e10 + CVh[1][0];    // exit of block
    const float ho1 = CAh[1][1] * e11 + CVh[1][1];
    if (q == 0) {                            // one lane per col
        __hip_atomic_store(&hpub[mbw * 1024 + ncol0], ho0,
                           __ATOMIC_RELAXED, __HIP_MEMORY_SCOPE_AGENT);
        __hip_atomic_store(&hpub[mbw * 1024 + ncol0 + 16], ho1,
                           __ATOMIC_RELAXED, __HIP_MEMORY_SCOPE_AGENT);
    }
    __syncthreads();                         // all waves' stores issued+drained
    if (tid == 0) {
        __threadfence();                     // belt-and-braces device release
        __hip_atomic_store(&flags[bid], 1, __ATOMIC_RELEASE,
                           __HIP_MEMORY_SCOPE_AGENT);
    }

    // ---------------- replay from registers, write out ----------------
#pragma unroll
    for (int hh = 0; hh < 2; ++hh) {
#pragma unroll
        for (int gg = 0; gg < 2; ++gg) {
            float h = (hh == 0) ? (gg == 0 ? hin0 : hin1)
                                : (gg == 0 ? e10 : e11);
            const int ncol = ncol0 + gg * 16;
#pragma unroll
            for (int mm = 0; mm < 4; ++mm) {
#pragma unroll
                for (int qt = 0; qt < 4; ++qt) {
                    if (q == qt) {
#pragma unroll
                        for (int rr = 0; rr < 4; ++rr) {
                            float2 p = __half22float2(av[(gg * 2 + hh) * 16 + mm * 4 + rr]);
                            h = p.x * h + p.y;
                            out[(size_t)(mrow0 + (hh * 4 + mm) * 16 + qt * 4 + rr) * H_ + ncol] = h;
                        }
                    }
                    h = __shfl(h, qt * 16 + r16);   // broadcast chain state
                }
            }
        }
    }
#undef LOADK
#undef MFMA32
}

// ---------------- launch ----------------
extern "C" void kernel_launch(void* const* d_in, const int* in_sizes, int n_in,
                              void* d_out, int out_size, void* d_ws, size_t ws_size,
                              hipStream_t stream) {
    const float* x  = (const float*)d_in[0];   // [B,T,D]
    const float* h0 = (const float*)d_in[1];   // [B,H]
    const float* Wz = (const float*)d_in[2];   // [H,D]
    const float* bz = (const float*)d_in[3];   // [H]
    const float* Wh = (const float*)d_in[4];   // [H,D]
    const float* bh = (const float*)d_in[5];   // [H]
    float* out = (float*)d_out;

    // workspace layout (bytes):
    //   xbp  bf16 perm [M][D]      @ 0            33,554,432
    //   wcbp bf16 perm [2048][D]   @ 33554432      4,194,304
    //   hpub fp32 [128][1024]      @ 37748736        524,288
    //   flags int [1024]           @ 38273024          4,096
    char* ws = (char*)d_ws;
    unsigned short* xbp  = (unsigned short*)(ws);
    unsigned short* wcbp = (unsigned short*)(ws + 33554432);
    float* hpub          = (float*)(ws + 37748736);
    int*   flags         = (int*)(ws + 38273024);

    hipMemsetAsync(flags, 0, 1024 * sizeof(int), stream);

    // 2,097,152 (x) + 262,144 (wcb) lane-slots = 2,359,296 threads = 9216 blocks
    convert_all<<<9216, 256, 0, stream>>>(x, Wz, Wh, xbp, wcbp);

    gemm_scan_kernel<<<1024, 256, 0, stream>>>(xbp, wcbp, bz, bh, h0,
                                               hpub, flags, out);
}